// Round 18
// baseline (193.348 us; speedup 1.0000x reference)
//
#include <hip/hip_runtime.h>

#define NCC_EPS 1.1920929e-07f

// ===========================================================================
// Scale-0 UNIFIED kernel: one load path for all 120 tiles.
//  - Interior tiles (th 1..10, tw 1..8) read the ORIGINAL volume; all H/W
//    accesses in-bounds by construction; D-halo via a zu-in-[0,D) branch
//    that zeros the registers (r12-interior proven codegen).
//  - Edge tiles read a compact pre-padded edge buffer [slot][160][24][24]
//    (H/W zero-padded); same body, block-uniform (base, pstr) only.
//  Body = r16 pad3: W phase (threads 0..95 slice A, 96..191 slice B,
//  register W-sliding sums -> wb), bar1, Hslide (128 threads, 4 H-outputs
//  each via 9-row sliding window -> hw), bar2, ring phase (256 threads,
//  1 b128 + 1 b32 per slice), clobber-free lgkmcnt(0)+s_barrier seams,
//  T14 register prefetch of the next pair's slices.
// ===========================================================================
template<int WIN>
__global__ __launch_bounds__(256)
void ncc_uni_kernel(const float* __restrict__ I, const float* __restrict__ J,
                    const float* __restrict__ EBI, const float* __restrict__ EBJ,
                    int D, int H, int W,
                    int tilesH, int tilesW, int chunksD, int chunkLen,
                    double* __restrict__ acc)
{
    constexpr int RAD  = WIN / 2;
    constexpr int TH = 16, TW = 16;
    constexpr int WROWS = TH + 2 * RAD;       // 24 wb rows
    constexpr int PSTR = 68;
    constexpr int QSTR = 16;
    constexpr int HSTR = 68;
    constexpr int H4STR = 16;
    constexpr int OFF  = 4 - RAD;
    constexpr int NWT  = WROWS * 4;           // 96 W-threads per slice
    constexpr float invV = 1.0f / (float)(WIN * WIN * WIN);

    __shared__ __align__(16) float wb0123[2][WROWS * PSTR];
    __shared__ __align__(16) float wb4[2][WROWS * QSTR];
    __shared__ __align__(16) float hw0123[2][TH * HSTR];
    __shared__ __align__(16) float hw4[2][TH * H4STR];
    __shared__ float red[4];

    int bid = blockIdx.x;
    int tw = bid % tilesW; bid /= tilesW;
    int th = bid % tilesH; bid /= tilesH;
    int cd = bid % chunksD; bid /= chunksD;
    int b  = bid;

    const int h0 = th * TH, w0 = tw * TW;
    const int z0 = cd * chunkLen;
    const int z1 = min(z0 + chunkLen, D);

    const int plane = H * W;

    const int t  = threadIdx.x;
    const int hh = t >> 4, ww = t & 15;
    const bool valid = (w0 + ww) < W;         // H exact-tiled

    const int wsl  = (t >= NWT) ? 1 : 0;
    const bool wact = t < 2 * NWT;
    const int wt  = t - NWT * wsl;
    const int wr  = wt >> 2;
    const int wc4 = wt & 3;

    // ---- block-uniform source select: interior -> original, edge -> EB ----
    const bool isEdge = (th == 0) || (th == tilesH - 1) ||
                        (tw == 0) || (tw == tilesW - 1);
    const float *baseI, *baseJ;
    int pstr;
    if (isEdge) {
        int e = (tw == 0) ? th
              : (tw == tilesW - 1) ? 12 + th
              : (th == 0) ? 24 + (tw - 1)
              : 32 + (tw - 1);
        size_t slot = (size_t)(e * 2 + b) * (size_t)(160 * 576);
        int off = wr * 24 + 4 * wc4;
        baseI = EBI + slot + off;
        baseJ = EBJ + slot + off;
        pstr = 576;
    } else {
        size_t off = (size_t)b * D * plane
                   + (size_t)(h0 - 4 + wr) * W + (w0 - 4 + 4 * wc4);
        baseI = I + off;
        baseJ = J + off;
        pstr = plane;
    }

    // Hslide mapping
    const bool hact = t < 128;
    const int hs = t >> 6;
    const int hc = t & 15;
    const int hg = (t >> 4) & 3;

    // zu = unpadded slice index (per-thread: depends on wsl)
    auto load_slice = [&](int zu, float (&fi)[12], float (&fj)[12]) {
        if (wact) {
            if (zu >= 0 && zu < D) {
                const float* rI = baseI + (size_t)zu * pstr;
                const float* rJ = baseJ + (size_t)zu * pstr;
                float4 a0 = *reinterpret_cast<const float4*>(rI);
                float4 a1 = *reinterpret_cast<const float4*>(rI + 4);
                float4 a2 = *reinterpret_cast<const float4*>(rI + 8);
                float4 b0 = *reinterpret_cast<const float4*>(rJ);
                float4 b1 = *reinterpret_cast<const float4*>(rJ + 4);
                float4 b2 = *reinterpret_cast<const float4*>(rJ + 8);
                fi[0]=a0.x; fi[1]=a0.y; fi[2]=a0.z; fi[3]=a0.w;
                fi[4]=a1.x; fi[5]=a1.y; fi[6]=a1.z; fi[7]=a1.w;
                fi[8]=a2.x; fi[9]=a2.y; fi[10]=a2.z; fi[11]=a2.w;
                fj[0]=b0.x; fj[1]=b0.y; fj[2]=b0.z; fj[3]=b0.w;
                fj[4]=b1.x; fj[5]=b1.y; fj[6]=b1.z; fj[7]=b1.w;
                fj[8]=b2.x; fj[9]=b2.y; fj[10]=b2.z; fj[11]=b2.w;
            } else {
                #pragma unroll
                for (int e2 = 0; e2 < 12; ++e2) { fi[e2] = 0.f; fj[e2] = 0.f; }
            }
        }
    };

    float ring[WIN][5];
    float rs[5];
    #pragma unroll
    for (int s = 0; s < WIN; ++s)
        #pragma unroll
        for (int c = 0; c < 5; ++c) ring[s][c] = 0.f;
    #pragma unroll
    for (int c = 0; c < 5; ++c) rs[c] = 0.f;

    float ccsum = 0.f;

    float fiC[12], fjC[12], fiN[12], fjN[12];
    const int zstart = z0 - RAD;
    const int zend   = z1 + RAD;
    load_slice(zstart + wsl, fiC, fjC);

    for (int zb = zstart; zb < zend; zb += 2 * WIN) {
        #pragma unroll
        for (int i = 0; i < WIN; ++i) {
            const int z = zb + 2 * i;          // slice A (uniform)
            if (z < zend) {
                const bool haveB = (z + 1 < zend);   // uniform
                // ---- 1) prefetch own slice of next pair ----
                load_slice(z + wsl + 2, fiN, fjN);

                // ---- 2) W phase: both slices concurrently -> wb ----
                if (wact) {
                    float s0 = 0, s1 = 0, s2 = 0, s3 = 0, s4 = 0;
                    #pragma unroll
                    for (int k = 0; k < WIN; ++k) {
                        float a = fiC[OFF + k], bb = fjC[OFF + k];
                        s0 += a; s1 += bb;
                        s2 = fmaf(a, a, s2);
                        s3 = fmaf(bb, bb, s3);
                        s4 = fmaf(bb, a, s4);
                    }
                    float o0[4], o1[4], o2[4], o3[4], o4[4];
                    o0[0]=s0; o1[0]=s1; o2[0]=s2; o3[0]=s3; o4[0]=s4;
                    #pragma unroll
                    for (int m = 1; m < 4; ++m) {
                        float aL = fiC[OFF + m - 1],       bL = fjC[OFF + m - 1];
                        float aR = fiC[OFF + m - 1 + WIN], bR = fjC[OFF + m - 1 + WIN];
                        s0 += aR - aL;
                        s1 += bR - bL;
                        s2 = s2 + aR * aR - aL * aL;
                        s3 = s3 + bR * bR - bL * bL;
                        s4 = s4 + aR * bR - aL * bL;
                        o0[m]=s0; o1[m]=s1; o2[m]=s2; o3[m]=s3; o4[m]=s4;
                    }
                    float* wbW = &wb0123[wsl][0];
                    float* w4W = &wb4[wsl][0];
                    #pragma unroll
                    for (int m = 0; m < 4; ++m) {
                        *reinterpret_cast<float4*>(&wbW[wr * PSTR + 16 * wc4 + 4 * m]) =
                            make_float4(o0[m], o1[m], o2[m], o3[m]);
                    }
                    *reinterpret_cast<float4*>(&w4W[wr * QSTR + 4 * wc4]) =
                        make_float4(o4[0], o4[1], o4[2], o4[3]);
                }
                // ---- 3) bar1 (clobber-free) ----
                __builtin_amdgcn_sched_barrier(0);
                asm volatile("s_waitcnt lgkmcnt(0)");
                __builtin_amdgcn_s_barrier();
                __builtin_amdgcn_sched_barrier(0);
                // ---- 4) Hslide: 4 H-outputs per thread ----
                if (hact) {
                    const float* wbS = &wb0123[hs][0];
                    const float* w4S = &wb4[hs][0];
                    float* hwS = &hw0123[hs][0];
                    float* h4S = &hw4[hs][0];
                    const int r0 = 4 * hg;
                    float4 a4 = make_float4(0.f, 0.f, 0.f, 0.f);
                    float a1 = 0.f;
                    float4 st4[3]; float st1[3];
                    #pragma unroll
                    for (int j = 0; j < WIN; ++j) {
                        float4 v = *reinterpret_cast<const float4*>(
                            &wbS[(r0 + j) * PSTR + 4 * hc]);
                        float w = w4S[(r0 + j) * QSTR + hc];
                        a4.x += v.x; a4.y += v.y; a4.z += v.z; a4.w += v.w;
                        a1 += w;
                        if (j < 3) { st4[j] = v; st1[j] = w; }
                    }
                    *reinterpret_cast<float4*>(&hwS[r0 * HSTR + 4 * hc]) = a4;
                    h4S[r0 * H4STR + hc] = a1;
                    #pragma unroll
                    for (int k = 1; k < 4; ++k) {
                        float4 vn = *reinterpret_cast<const float4*>(
                            &wbS[(r0 + WIN - 1 + k) * PSTR + 4 * hc]);
                        float wn = w4S[(r0 + WIN - 1 + k) * QSTR + hc];
                        a4.x += vn.x - st4[k - 1].x;
                        a4.y += vn.y - st4[k - 1].y;
                        a4.z += vn.z - st4[k - 1].z;
                        a4.w += vn.w - st4[k - 1].w;
                        a1 += wn - st1[k - 1];
                        *reinterpret_cast<float4*>(&hwS[(r0 + k) * HSTR + 4 * hc]) = a4;
                        h4S[(r0 + k) * H4STR + hc] = a1;
                    }
                }
                // ---- 5) bar2 (clobber-free) ----
                __builtin_amdgcn_sched_barrier(0);
                asm volatile("s_waitcnt lgkmcnt(0)");
                __builtin_amdgcn_s_barrier();
                __builtin_amdgcn_sched_barrier(0);
                // ---- 6) ring + emit, slice A ----
                {
                    float4 a4 = *reinterpret_cast<const float4*>(
                        &hw0123[0][hh * HSTR + 4 * ww]);
                    float nn4 = hw4[0][hh * H4STR + ww];
                    rs[0] += a4.x - ring[(2 * i) % WIN][0]; ring[(2 * i) % WIN][0] = a4.x;
                    rs[1] += a4.y - ring[(2 * i) % WIN][1]; ring[(2 * i) % WIN][1] = a4.y;
                    rs[2] += a4.z - ring[(2 * i) % WIN][2]; ring[(2 * i) % WIN][2] = a4.z;
                    rs[3] += a4.w - ring[(2 * i) % WIN][3]; ring[(2 * i) % WIN][3] = a4.w;
                    rs[4] += nn4  - ring[(2 * i) % WIN][4]; ring[(2 * i) % WIN][4] = nn4;
                    const int zo = z - RAD;
                    if (valid && zo >= z0) {
                        float muI = rs[0] * invV;
                        float muJ = rs[1] * invV;
                        float sII = rs[2] * invV - muI * muI;
                        float sJJ = rs[3] * invV - muJ * muJ;
                        float s12 = rs[4] * invV - muI * muJ;
                        float cc = (s12 * s12) / fmaxf(sII * sJJ, NCC_EPS);
                        ccsum += cc;
                    }
                }
                // ---- 7) ring + emit, slice B ----
                if (haveB) {
                    float4 a4 = *reinterpret_cast<const float4*>(
                        &hw0123[1][hh * HSTR + 4 * ww]);
                    float nn4 = hw4[1][hh * H4STR + ww];
                    rs[0] += a4.x - ring[(2 * i + 1) % WIN][0]; ring[(2 * i + 1) % WIN][0] = a4.x;
                    rs[1] += a4.y - ring[(2 * i + 1) % WIN][1]; ring[(2 * i + 1) % WIN][1] = a4.y;
                    rs[2] += a4.z - ring[(2 * i + 1) % WIN][2]; ring[(2 * i + 1) % WIN][2] = a4.z;
                    rs[3] += a4.w - ring[(2 * i + 1) % WIN][3]; ring[(2 * i + 1) % WIN][3] = a4.w;
                    rs[4] += nn4  - ring[(2 * i + 1) % WIN][4]; ring[(2 * i + 1) % WIN][4] = nn4;
                    const int zo = z + 1 - RAD;
                    if (valid && zo >= z0) {
                        float muI = rs[0] * invV;
                        float muJ = rs[1] * invV;
                        float sII = rs[2] * invV - muI * muI;
                        float sJJ = rs[3] * invV - muJ * muJ;
                        float s12 = rs[4] * invV - muI * muJ;
                        float cc = (s12 * s12) / fmaxf(sII * sJJ, NCC_EPS);
                        ccsum += cc;
                    }
                }
                // ---- 8) rotate prefetch regs ----
                #pragma unroll
                for (int e2 = 0; e2 < 12; ++e2) { fiC[e2] = fiN[e2]; fjC[e2] = fjN[e2]; }
            }
        }
    }

    for (int off = 32; off > 0; off >>= 1)
        ccsum += __shfl_down(ccsum, off);
    const int wid = t >> 6, lane = t & 63;
    if (lane == 0) red[wid] = ccsum;
    __syncthreads();
    if (t == 0) {
        float s = red[0] + red[1] + red[2] + red[3];
        atomicAdd(acc, (double)s);
    }
}

// Fill the 40 edge-tile buffers: slot = e*2+b, layout [slot][z:160][r:24][c:24]
// with H/W zero-padding (rows h0-4..h0+19, cols w0-4..w0+19 of the original).
__global__ void edgefill_kernel(const float* __restrict__ I, const float* __restrict__ J,
                                float* __restrict__ EBI, float* __restrict__ EBJ,
                                int D, int H, int W, int total)
{
    int idx = blockIdx.x * 256 + threadIdx.x;
    if (idx >= 2 * total) return;
    const bool isJ = idx >= total;
    int k = isJ ? idx - total : idx;
    const float* in = isJ ? J : I;
    float* out = isJ ? EBJ : EBI;

    int c = k % 6;  k /= 6;
    int r = k % 24; k /= 24;
    int z = k % 160; k /= 160;
    int slot = k;                      // 0..79
    int e = slot >> 1, b = slot & 1;

    int th, tw;
    if (e < 12)      { th = e;      tw = 0; }
    else if (e < 24) { th = e - 12; tw = 9; }
    else if (e < 32) { th = 0;      tw = e - 24 + 1; }
    else             { th = 11;     tw = e - 32 + 1; }

    const int h = th * 16 - 4 + r;
    const int w0c = tw * 16 - 4 + 4 * c;

    float4 v = make_float4(0.f, 0.f, 0.f, 0.f);
    if (h >= 0 && h < H) {
        const float* row = in + ((size_t)(b * D + z) * H + h) * W;
        if (w0c >= 0 && w0c + 4 <= W) {
            v = *reinterpret_cast<const float4*>(row + w0c);
        } else {
            float tmp[4];
            #pragma unroll
            for (int q = 0; q < 4; ++q) {
                int wq = w0c + q;
                tmp[q] = (wq >= 0 && wq < W) ? row[wq] : 0.f;
            }
            v = make_float4(tmp[0], tmp[1], tmp[2], tmp[3]);
        }
    }
    *reinterpret_cast<float4*>(&out[((size_t)slot * 160 + z) * 576 + r * 24 + 4 * c]) = v;
}

// ===========================================================================
// Padded-pyramid NCC (1 slice/barrier) for scales 1/2 (unchanged).
// ===========================================================================
template<int WIN>
__global__ __launch_bounds__(256)
void ncc_pad_kernel(const float* __restrict__ Pi, const float* __restrict__ Pj,
                    int Dp, int Hp, int Wp, int Dreal, int Wreal,
                    int tilesH, int tilesW, int chunksD, int chunkLen,
                    double* __restrict__ acc)
{
    constexpr int RAD  = WIN / 2;
    constexpr int TH = 16, TW = 16;
    constexpr int WROWS = TH + 2 * RAD;
    constexpr int PSTR = 68;
    constexpr int QSTR = 16;
    constexpr int OFF  = 4 - RAD;
    constexpr int NWT  = WROWS * 4;
    constexpr float invV = 1.0f / (float)(WIN * WIN * WIN);

    __shared__ __align__(16) float wb0123[2][WROWS * PSTR];
    __shared__ __align__(16) float wb4[2][WROWS * QSTR];
    __shared__ float red[4];

    int bid = blockIdx.x;
    int tw = bid % tilesW; bid /= tilesW;
    int th = bid % tilesH; bid /= tilesH;
    int cd = bid % chunksD; bid /= chunksD;
    int b  = bid;

    const int h0 = th * TH, w0 = tw * TW;
    const int z0 = cd * chunkLen;
    const int z1 = min(z0 + chunkLen, Dreal);

    const size_t plane = (size_t)Hp * Wp;
    const float* Ib = Pi + (size_t)b * Dp * plane;
    const float* Jb = Pj + (size_t)b * Dp * plane;

    const int t  = threadIdx.x;
    const int hh = t >> 4, ww = t & 15;
    const bool valid = (w0 + ww) < Wreal;

    const int wr  = t >> 2;
    const int wc4 = t & 3;
    const bool wact = t < NWT;
    const size_t rowoff = (size_t)(h0 + wr) * Wp + (w0 + 4 * wc4);

    auto load_slice = [&](int zp, float (&fi)[12], float (&fj)[12]) {
        if (wact) {
            const float* rI = Ib + (size_t)zp * plane + rowoff;
            const float* rJ = Jb + (size_t)zp * plane + rowoff;
            float4 a0 = *reinterpret_cast<const float4*>(rI);
            float4 a1 = *reinterpret_cast<const float4*>(rI + 4);
            float4 a2 = *reinterpret_cast<const float4*>(rI + 8);
            float4 b0 = *reinterpret_cast<const float4*>(rJ);
            float4 b1 = *reinterpret_cast<const float4*>(rJ + 4);
            float4 b2 = *reinterpret_cast<const float4*>(rJ + 8);
            fi[0]=a0.x; fi[1]=a0.y; fi[2]=a0.z; fi[3]=a0.w;
            fi[4]=a1.x; fi[5]=a1.y; fi[6]=a1.z; fi[7]=a1.w;
            fi[8]=a2.x; fi[9]=a2.y; fi[10]=a2.z; fi[11]=a2.w;
            fj[0]=b0.x; fj[1]=b0.y; fj[2]=b0.z; fj[3]=b0.w;
            fj[4]=b1.x; fj[5]=b1.y; fj[6]=b1.z; fj[7]=b1.w;
            fj[8]=b2.x; fj[9]=b2.y; fj[10]=b2.z; fj[11]=b2.w;
        }
    };

    float ring[WIN][5];
    float rs[5];
    #pragma unroll
    for (int s = 0; s < WIN; ++s)
        #pragma unroll
        for (int c = 0; c < 5; ++c) ring[s][c] = 0.f;
    #pragma unroll
    for (int c = 0; c < 5; ++c) rs[c] = 0.f;

    float ccsum = 0.f;

    float fiC[12], fjC[12], fiN[12], fjN[12];
    const int zend = z1 + RAD;
    load_slice(z0 - RAD + 4, fiC, fjC);

    for (int zb = z0 - RAD; zb < zend; zb += WIN) {
        #pragma unroll
        for (int ph = 0; ph < WIN; ++ph) {
            const int z = zb + ph;
            if (z < zend) {
                const int zpn = min(z + 5, Dp - 1);
                load_slice(zpn, fiN, fjN);

                const int par = (z + 4) & 1;
                float n0, n1, n2, n3, n4;
                if (wact) {
                    float s0 = 0, s1 = 0, s2 = 0, s3 = 0, s4 = 0;
                    #pragma unroll
                    for (int k = 0; k < WIN; ++k) {
                        float a = fiC[OFF + k], bb = fjC[OFF + k];
                        s0 += a; s1 += bb;
                        s2 = fmaf(a, a, s2);
                        s3 = fmaf(bb, bb, s3);
                        s4 = fmaf(a, bb, s4);
                    }
                    float o0[4], o1[4], o2[4], o3[4], o4[4];
                    o0[0]=s0; o1[0]=s1; o2[0]=s2; o3[0]=s3; o4[0]=s4;
                    #pragma unroll
                    for (int m = 1; m < 4; ++m) {
                        float aL = fiC[OFF + m - 1],       bL = fjC[OFF + m - 1];
                        float aR = fiC[OFF + m - 1 + WIN], bR = fjC[OFF + m - 1 + WIN];
                        s0 += aR - aL;
                        s1 += bR - bL;
                        s2 = s2 + aR * aR - aL * aL;
                        s3 = s3 + bR * bR - bL * bL;
                        s4 = s4 + aR * bR - aL * bL;
                        o0[m]=s0; o1[m]=s1; o2[m]=s2; o3[m]=s3; o4[m]=s4;
                    }
                    #pragma unroll
                    for (int m = 0; m < 4; ++m) {
                        *reinterpret_cast<float4*>(&wb0123[par][wr * PSTR + 16 * wc4 + 4 * m]) =
                            make_float4(o0[m], o1[m], o2[m], o3[m]);
                    }
                    *reinterpret_cast<float4*>(&wb4[par][wr * QSTR + 4 * wc4]) =
                        make_float4(o4[0], o4[1], o4[2], o4[3]);
                }
                __builtin_amdgcn_sched_barrier(0);
                asm volatile("s_waitcnt lgkmcnt(0)");
                __builtin_amdgcn_s_barrier();
                __builtin_amdgcn_sched_barrier(0);
                {
                    float4 a4 = make_float4(0.f, 0.f, 0.f, 0.f);
                    float nn4 = 0.f;
                    #pragma unroll
                    for (int dh = 0; dh < WIN; ++dh) {
                        float4 v = *reinterpret_cast<const float4*>(
                            &wb0123[par][(hh + dh) * PSTR + 4 * ww]);
                        a4.x += v.x; a4.y += v.y; a4.z += v.z; a4.w += v.w;
                        nn4 += wb4[par][(hh + dh) * QSTR + ww];
                    }
                    n0 = a4.x; n1 = a4.y; n2 = a4.z; n3 = a4.w; n4 = nn4;
                }
                rs[0] += n0 - ring[ph][0]; ring[ph][0] = n0;
                rs[1] += n1 - ring[ph][1]; ring[ph][1] = n1;
                rs[2] += n2 - ring[ph][2]; ring[ph][2] = n2;
                rs[3] += n3 - ring[ph][3]; ring[ph][3] = n3;
                rs[4] += n4 - ring[ph][4]; ring[ph][4] = n4;

                const int zo = z - RAD;
                if (valid && zo >= z0) {
                    float muI = rs[0] * invV;
                    float muJ = rs[1] * invV;
                    float sII = rs[2] * invV - muI * muI;
                    float sJJ = rs[3] * invV - muJ * muJ;
                    float s12 = rs[4] * invV - muI * muJ;
                    float cc = (s12 * s12) / fmaxf(sII * sJJ, NCC_EPS);
                    ccsum += cc;
                }
                #pragma unroll
                for (int e = 0; e < 12; ++e) { fiC[e] = fiN[e]; fjC[e] = fjN[e]; }
            }
        }
    }

    for (int off = 32; off > 0; off >>= 1)
        ccsum += __shfl_down(ccsum, off);
    const int wid = t >> 6, lane = t & 63;
    if (lane == 0) red[wid] = ccsum;
    __syncthreads();
    if (t == 0) {
        float s = red[0] + red[1] + red[2] + red[3];
        atomicAdd(acc, (double)s);
    }
}

// avg_pool3d from UNPADDED source -> padded destination (interior only).
__global__ void pool_b2p_kernel(const float* __restrict__ inA, const float* __restrict__ inB,
                                float* __restrict__ outA, float* __restrict__ outB,
                                int D, int H, int W, int oD, int oH, int oW,
                                int oDp, int oHp, int oWp, int total)
{
    int idx0 = blockIdx.x * 256 + threadIdx.x;
    if (idx0 >= 2 * total) return;
    const bool isB = idx0 >= total;
    int idx = isB ? idx0 - total : idx0;
    const float* in = isB ? inB : inA;
    float* out = isB ? outB : outA;

    int ow = idx % oW; int tmp = idx / oW;
    int oh = tmp % oH; tmp /= oH;
    int od = tmp % oD; int b = tmp / oD;

    int dlo = max(2 * od - 1, 0), dhi = min(2 * od + 2, D);
    int hlo = max(2 * oh - 1, 0), hhi = min(2 * oh + 2, H);
    int wlo = max(2 * ow - 1, 0), whi = min(2 * ow + 2, W);

    const float* ib = in + (size_t)b * D * H * W;
    float s = 0.f;
    for (int d = dlo; d < dhi; ++d)
        for (int h = hlo; h < hhi; ++h)
            for (int w = wlo; w < whi; ++w)
                s += ib[((size_t)d * H + h) * W + w];
    int cnt = (dhi - dlo) * (hhi - hlo) * (whi - wlo);
    out[((size_t)(b * oDp + od + 4) * oHp + (oh + 4)) * oWp + (ow + 4)] = s / (float)cnt;
}

// avg_pool3d padded source -> padded destination (interior only).
__global__ void pool_pad_kernel(const float* __restrict__ inA, const float* __restrict__ inB,
                                float* __restrict__ outA, float* __restrict__ outB,
                                int D, int H, int W, int iDp, int iHp, int iWp,
                                int oD, int oH, int oW, int oDp, int oHp, int oWp,
                                int total)
{
    int idx0 = blockIdx.x * 256 + threadIdx.x;
    if (idx0 >= 2 * total) return;
    const bool isB = idx0 >= total;
    int idx = isB ? idx0 - total : idx0;
    const float* in = isB ? inB : inA;
    float* out = isB ? outB : outA;

    int ow = idx % oW; int tmp = idx / oW;
    int oh = tmp % oH; tmp /= oH;
    int od = tmp % oD; int b = tmp / oD;

    const size_t ip = (size_t)iHp * iWp;
    const float* ib = in + (size_t)b * iDp * ip;
    float s = 0.f;
    #pragma unroll
    for (int dd = 0; dd < 3; ++dd)
        #pragma unroll
        for (int dh = 0; dh < 3; ++dh) {
            const float* r = ib + (size_t)(2 * od + 3 + dd) * ip
                                + (size_t)(2 * oh + 3 + dh) * iWp + (2 * ow + 3);
            s += r[0] + r[1] + r[2];
        }
    int dlo = max(2 * od - 1, 0), dhi = min(2 * od + 2, D);
    int hlo = max(2 * oh - 1, 0), hhi = min(2 * oh + 2, H);
    int wlo = max(2 * ow - 1, 0), whi = min(2 * ow + 2, W);
    int cnt = (dhi - dlo) * (hhi - hlo) * (whi - wlo);
    out[((size_t)(b * oDp + od + 4) * oHp + (oh + 4)) * oWp + (ow + 4)] = s / (float)cnt;
}

// ===========================================================================
// FALLBACK PATH (small workspace): bounded kernel, verified passing.
// ===========================================================================
template<int WIN>
__global__ __launch_bounds__(256)
void ncc_scale_kernel(const float* __restrict__ I, const float* __restrict__ J,
                      int D, int H, int W,
                      int tilesH, int tilesW, int chunksD, int chunkLen,
                      double* __restrict__ acc)
{
    constexpr int RAD  = WIN / 2;
    constexpr int TH = 16, TW = 16;
    constexpr int WROWS = TH + 2 * RAD;
    constexpr int PSTR = 68;
    constexpr int QSTR = 16;
    constexpr int OFF  = 4 - RAD;
    constexpr int NWT  = WROWS * 4;
    constexpr float invV = 1.0f / (float)(WIN * WIN * WIN);

    __shared__ __align__(16) float wb0123[2][WROWS * PSTR];
    __shared__ __align__(16) float wb4[2][WROWS * QSTR];
    __shared__ float red[4];

    int bid = blockIdx.x;
    int tw = bid % tilesW; bid /= tilesW;
    int th = bid % tilesH; bid /= tilesH;
    int cd = bid % chunksD; bid /= chunksD;
    int b  = bid;

    const int h0 = th * TH, w0 = tw * TW;
    const int z0 = cd * chunkLen;
    const int z1 = min(z0 + chunkLen, D);

    const size_t plane = (size_t)H * W;
    const float* Ib = I + (size_t)b * D * plane;
    const float* Jb = J + (size_t)b * D * plane;

    const int t  = threadIdx.x;
    const int hh = t >> 4, ww = t & 15;
    const bool valid = (h0 + hh) < H && (w0 + ww) < W;

    const int wr  = t >> 2;
    const int wc4 = t & 3;
    const bool wact = t < NWT;
    const int wbase = w0 + 4 * wc4 - 4;
    const int wghr  = h0 + wr - RAD;

    auto load_slice = [&](int z, float (&fi)[12], float (&fj)[12]) {
        const bool zok = (z >= 0) && (z < D);
        if (zok && wact && wghr >= 0 && wghr < H) {
            const float* rowI = Ib + (size_t)z * plane + (size_t)wghr * W;
            const float* rowJ = Jb + (size_t)z * plane + (size_t)wghr * W;
            if (wbase >= 0 && wbase + 12 <= W) {
                float4 a0 = *reinterpret_cast<const float4*>(rowI + wbase);
                float4 a1 = *reinterpret_cast<const float4*>(rowI + wbase + 4);
                float4 a2 = *reinterpret_cast<const float4*>(rowI + wbase + 8);
                float4 b0 = *reinterpret_cast<const float4*>(rowJ + wbase);
                float4 b1 = *reinterpret_cast<const float4*>(rowJ + wbase + 4);
                float4 b2 = *reinterpret_cast<const float4*>(rowJ + wbase + 8);
                fi[0]=a0.x; fi[1]=a0.y; fi[2]=a0.z; fi[3]=a0.w;
                fi[4]=a1.x; fi[5]=a1.y; fi[6]=a1.z; fi[7]=a1.w;
                fi[8]=a2.x; fi[9]=a2.y; fi[10]=a2.z; fi[11]=a2.w;
                fj[0]=b0.x; fj[1]=b0.y; fj[2]=b0.z; fj[3]=b0.w;
                fj[4]=b1.x; fj[5]=b1.y; fj[6]=b1.z; fj[7]=b1.w;
                fj[8]=b2.x; fj[9]=b2.y; fj[10]=b2.z; fj[11]=b2.w;
            } else {
                #pragma unroll
                for (int e = 0; e < 12; ++e) {
                    int cg = wbase + e;
                    bool ok = (cg >= 0) && (cg < W);
                    fi[e] = ok ? rowI[cg] : 0.f;
                    fj[e] = ok ? rowJ[cg] : 0.f;
                }
            }
        } else {
            #pragma unroll
            for (int e = 0; e < 12; ++e) { fi[e] = 0.f; fj[e] = 0.f; }
        }
    };

    float ring[WIN][5];
    float rs[5];
    #pragma unroll
    for (int s = 0; s < WIN; ++s)
        #pragma unroll
        for (int c = 0; c < 5; ++c) ring[s][c] = 0.f;
    #pragma unroll
    for (int c = 0; c < 5; ++c) rs[c] = 0.f;

    float ccsum = 0.f;

    float fiC[12], fjC[12], fiN[12], fjN[12];
    const int zend = z1 + RAD;
    load_slice(z0 - RAD, fiC, fjC);

    for (int zb = z0 - RAD; zb < zend; zb += WIN) {
        #pragma unroll
        for (int ph = 0; ph < WIN; ++ph) {
            const int z = zb + ph;
            if (z < zend) {
                const bool zin = (z >= 0) && (z < D);
                load_slice((z + 1 < zend) ? z + 1 : -1, fiN, fjN);
                float n0 = 0, n1 = 0, n2 = 0, n3 = 0, n4 = 0;
                if (zin) {
                    const int par = (z + 64) & 1;
                    if (wact) {
                        float s0 = 0, s1 = 0, s2 = 0, s3 = 0, s4 = 0;
                        #pragma unroll
                        for (int k = 0; k < WIN; ++k) {
                            float a = fiC[OFF + k], bb = fjC[OFF + k];
                            s0 += a; s1 += bb;
                            s2 = fmaf(a, a, s2);
                            s3 = fmaf(bb, bb, s3);
                            s4 = fmaf(a, bb, s4);
                        }
                        float o0[4], o1[4], o2[4], o3[4], o4[4];
                        o0[0]=s0; o1[0]=s1; o2[0]=s2; o3[0]=s3; o4[0]=s4;
                        #pragma unroll
                        for (int m = 1; m < 4; ++m) {
                            float aL = fiC[OFF + m - 1],       bL = fjC[OFF + m - 1];
                            float aR = fiC[OFF + m - 1 + WIN], bR = fjC[OFF + m - 1 + WIN];
                            s0 += aR - aL;
                            s1 += bR - bL;
                            s2 = s2 + aR * aR - aL * aL;
                            s3 = s3 + bR * bR - bL * bL;
                            s4 = s4 + aR * bR - aL * bL;
                            o0[m]=s0; o1[m]=s1; o2[m]=s2; o3[m]=s3; o4[m]=s4;
                        }
                        #pragma unroll
                        for (int m = 0; m < 4; ++m) {
                            *reinterpret_cast<float4*>(&wb0123[par][wr * PSTR + 16 * wc4 + 4 * m]) =
                                make_float4(o0[m], o1[m], o2[m], o3[m]);
                        }
                        *reinterpret_cast<float4*>(&wb4[par][wr * QSTR + 4 * wc4]) =
                            make_float4(o4[0], o4[1], o4[2], o4[3]);
                    }
                    __syncthreads();
                    float4 a4 = make_float4(0.f, 0.f, 0.f, 0.f);
                    #pragma unroll
                    for (int dh = 0; dh < WIN; ++dh) {
                        float4 v = *reinterpret_cast<const float4*>(
                            &wb0123[par][(hh + dh) * PSTR + 4 * ww]);
                        a4.x += v.x; a4.y += v.y; a4.z += v.z; a4.w += v.w;
                        n4 += wb4[par][(hh + dh) * QSTR + ww];
                    }
                    n0 = a4.x; n1 = a4.y; n2 = a4.z; n3 = a4.w;
                }
                rs[0] += n0 - ring[ph][0]; ring[ph][0] = n0;
                rs[1] += n1 - ring[ph][1]; ring[ph][1] = n1;
                rs[2] += n2 - ring[ph][2]; ring[ph][2] = n2;
                rs[3] += n3 - ring[ph][3]; ring[ph][3] = n3;
                rs[4] += n4 - ring[ph][4]; ring[ph][4] = n4;

                const int zo = z - RAD;
                if (valid && zo >= z0) {
                    float muI = rs[0] * invV;
                    float muJ = rs[1] * invV;
                    float sII = rs[2] * invV - muI * muI;
                    float sJJ = rs[3] * invV - muJ * muJ;
                    float s12 = rs[4] * invV - muI * muJ;
                    float cc = (s12 * s12) / fmaxf(sII * sJJ, NCC_EPS);
                    ccsum += cc;
                }
                #pragma unroll
                for (int e = 0; e < 12; ++e) { fiC[e] = fiN[e]; fjC[e] = fjN[e]; }
            }
        }
    }

    for (int off = 32; off > 0; off >>= 1)
        ccsum += __shfl_down(ccsum, off);
    const int wid = t >> 6, lane = t & 63;
    if (lane == 0) red[wid] = ccsum;
    __syncthreads();
    if (t == 0) {
        float s = red[0] + red[1] + red[2] + red[3];
        atomicAdd(acc, (double)s);
    }
}

__global__ void pool_kernel2(const float* __restrict__ inA, const float* __restrict__ inB,
                             float* __restrict__ outA, float* __restrict__ outB,
                             int D, int H, int W, int oD, int oH, int oW, int total)
{
    int idx0 = blockIdx.x * 256 + threadIdx.x;
    if (idx0 >= 2 * total) return;
    const bool isB = idx0 >= total;
    int idx = isB ? idx0 - total : idx0;
    const float* in = isB ? inB : inA;
    float* out = isB ? outB : outA;

    int ow = idx % oW; int tmp = idx / oW;
    int oh = tmp % oH; tmp /= oH;
    int od = tmp % oD; int b = tmp / oD;

    int dlo = max(2 * od - 1, 0), dhi = min(2 * od + 2, D);
    int hlo = max(2 * oh - 1, 0), hhi = min(2 * oh + 2, H);
    int wlo = max(2 * ow - 1, 0), whi = min(2 * ow + 2, W);

    const float* ib = in + (size_t)b * D * H * W;
    float s = 0.f;
    for (int d = dlo; d < dhi; ++d)
        for (int h = hlo; h < hhi; ++h)
            for (int w = wlo; w < whi; ++w)
                s += ib[((size_t)d * H + h) * W + w];
    int cnt = (dhi - dlo) * (hhi - hlo) * (whi - wlo);
    out[idx] = s / (float)cnt;
}

__global__ void finalize_kernel(const double* __restrict__ acc, float* __restrict__ out)
{
    double m = acc[0] / 9830400.0 + acc[1] / 1228800.0 + acc[2] / 153600.0;
    out[0] = (float)(-m / 3.0);
}

extern "C" void kernel_launch(void* const* d_in, const int* in_sizes, int n_in,
                              void* d_out, int out_size, void* d_ws, size_t ws_size,
                              hipStream_t stream)
{
    const float* I0 = (const float*)d_in[0];
    const float* J0 = (const float*)d_in[1];
    float* out = (float*)d_out;

    char* ws = (char*)d_ws;
    double* acc = (double*)ws;
    hipMemsetAsync(acc, 0, 3 * sizeof(double), stream);

    const size_t EBSZ = (size_t)80 * 160 * 576;        // 7,372,800 floats/array
    const size_t P1SZ = (size_t)2 * 88 * 104 * 88;     // 1,610,752 floats/array
    const size_t P2SZ = (size_t)2 * 48 * 56 * 56;      //   301,056 floats/array
    const size_t need = 256 + (2 * EBSZ + 2 * P1SZ + 2 * P2SZ) * sizeof(float);

    if (ws_size >= need) {
        // ---------------- MAIN PATH (unified s0, edge buffers) ----------
        float* EBI = (float*)(ws + 256);
        float* EBJ = EBI + EBSZ;
        float* P1I = EBJ + EBSZ;
        float* P1J = P1I + P1SZ;
        float* P2I = P1J + P1SZ;
        float* P2J = P2I + P2SZ;

        hipMemsetAsync(P1I, 0, (2 * P1SZ + 2 * P2SZ) * sizeof(float), stream);

        // fill edge-tile buffers (H/W-padded 24x24 windows, 40 tiles x 2b)
        {
            int total = 80 * 160 * 24 * 6;             // float4 units/array
            int blocks = (2 * total + 255) / 256;
            edgefill_kernel<<<blocks, 256, 0, stream>>>(I0, J0, EBI, EBJ,
                                                        160, 192, 160, total);
        }
        // scale 0: unified 2-slice + hierarchical-H, 960 blocks
        ncc_uni_kernel<9><<<2 * 12 * 10 * 4, 256, 0, stream>>>(
            I0, J0, EBI, EBJ, 160, 192, 160, 12, 10, 4, 40, acc + 0);
        // pool 0 -> 1 (original -> padded P1)
        {
            int total = 2 * 80 * 96 * 80;
            int blocks = (2 * total + 255) / 256;
            pool_b2p_kernel<<<blocks, 256, 0, stream>>>(I0, J0, P1I, P1J,
                                                        160, 192, 160, 80, 96, 80,
                                                        88, 104, 88, total);
        }
        // scale 1: win=7 (padded)
        ncc_pad_kernel<7><<<2 * 6 * 5 * 10, 256, 0, stream>>>(
            P1I, P1J, 88, 104, 88, 80, 80, 6, 5, 10, 8, acc + 1);
        // pool 1 -> 2 (padded -> padded)
        {
            int total = 2 * 40 * 48 * 40;
            int blocks = (2 * total + 255) / 256;
            pool_pad_kernel<<<blocks, 256, 0, stream>>>(P1I, P1J, P2I, P2J,
                                                        80, 96, 80, 88, 104, 88,
                                                        40, 48, 40, 48, 56, 56, total);
        }
        // scale 2: win=5 (padded)
        ncc_pad_kernel<5><<<2 * 3 * 3 * 10, 256, 0, stream>>>(
            P2I, P2J, 48, 56, 56, 40, 40, 3, 3, 10, 4, acc + 2);
    } else {
        // ---------------- FALLBACK (bounded path) ----------------
        float* I1 = (float*)(ws + 256);
        float* J1 = I1 + (size_t)2 * 80 * 96 * 80;
        float* I2 = J1 + (size_t)2 * 80 * 96 * 80;
        float* J2 = I2 + (size_t)2 * 40 * 48 * 40;

        ncc_scale_kernel<9><<<2 * 12 * 10 * 6, 256, 0, stream>>>(
            I0, J0, 160, 192, 160, 12, 10, 6, 27, acc + 0);
        {
            int total = 2 * 80 * 96 * 80;
            int blocks = (2 * total + 255) / 256;
            pool_kernel2<<<blocks, 256, 0, stream>>>(I0, J0, I1, J1,
                                                     160, 192, 160, 80, 96, 80, total);
        }
        ncc_scale_kernel<7><<<2 * 6 * 5 * 10, 256, 0, stream>>>(
            I1, J1, 80, 96, 80, 6, 5, 10, 8, acc + 1);
        {
            int total = 2 * 40 * 48 * 40;
            int blocks = (2 * total + 255) / 256;
            pool_kernel2<<<blocks, 256, 0, stream>>>(I1, J1, I2, J2,
                                                     80, 96, 80, 40, 48, 40, total);
        }
        ncc_scale_kernel<5><<<2 * 3 * 3 * 10, 256, 0, stream>>>(
            I2, J2, 40, 48, 40, 3, 3, 10, 4, acc + 2);
    }

    finalize_kernel<<<1, 1, 0, stream>>>(acc, out);
}

// Round 19
// 168.765 us; speedup vs baseline: 1.1457x; 1.1457x over previous
//
#include <hip/hip_runtime.h>

#define NCC_EPS 1.1920929e-07f

// ===========================================================================
// PADDED PATH (round-16 champion, reverted after r17/r18 regression).
// Scale 0: 2-slice kernel with HIERARCHICAL H:
//   phase W (threads 0..95 slice A, 96..191 slice B): register W-sliding
//     sums -> wb (single-buffered).
//   bar1 (clobber-free lgkmcnt(0)+s_barrier; prefetch vmcnt stays in flight)
//   phase Hslide (threads 0..127, 64 per slice): each thread owns (col c,
//     row-group g) and computes 4 H-outputs by sliding a 9-row window over
//     wb (rows read once, first 3 stashed in regs) -> hw buffer.
//   bar2
//   phase ring (all 256): read finished 5-tuple (1 b128 + 1 b32) per slice,
//     D-ring update, emit cc.
// Single-buffer safety: any wave in iter i+1 phase X passed the barrier that
// orders it after ALL waves' prior-phase accesses (each wave's lgkmcnt(0)
// precedes its barrier).
// Banks (lane-derived): Hslide/ring b128 at the 8-word/bank floor; hw4/ring
// b32 2-way (free); wb4 Hslide reads 4-way (1.58x, 12 ops, minor).
// ===========================================================================
template<int WIN>
__global__ __launch_bounds__(256)
void ncc_pad3_kernel(const float* __restrict__ Pi, const float* __restrict__ Pj,
                     int Dp, int Hp, int Wp, int Dreal, int Wreal,
                     int tilesH, int tilesW, int chunksD, int chunkLen,
                     double* __restrict__ acc)
{
    constexpr int RAD  = WIN / 2;
    constexpr int TH = 16, TW = 16;
    constexpr int WROWS = TH + 2 * RAD;       // 24 wb rows
    constexpr int PSTR = 68;                  // wb0123 row stride
    constexpr int QSTR = 16;                  // wb4 row stride
    constexpr int HSTR = 68;                  // hw0123 row stride
    constexpr int H4STR = 16;                 // hw4 row stride
    constexpr int OFF  = 4 - RAD;
    constexpr int NWT  = WROWS * 4;           // 96 W-threads per slice
    constexpr float invV = 1.0f / (float)(WIN * WIN * WIN);

    __shared__ __align__(16) float wb0123[2][WROWS * PSTR];
    __shared__ __align__(16) float wb4[2][WROWS * QSTR];
    __shared__ __align__(16) float hw0123[2][TH * HSTR];
    __shared__ __align__(16) float hw4[2][TH * H4STR];
    __shared__ float red[4];

    int bid = blockIdx.x;
    int tw = bid % tilesW; bid /= tilesW;
    int th = bid % tilesH; bid /= tilesH;
    int cd = bid % chunksD; bid /= chunksD;
    int b  = bid;

    const int h0 = th * TH, w0 = tw * TW;
    const int z0 = cd * chunkLen;
    const int z1 = min(z0 + chunkLen, Dreal);

    const size_t plane = (size_t)Hp * Wp;
    const float* Ib = Pi + (size_t)b * Dp * plane;
    const float* Jb = Pj + (size_t)b * Dp * plane;

    const int t  = threadIdx.x;
    const int hh = t >> 4, ww = t & 15;
    const bool valid = (w0 + ww) < Wreal;     // H exact-tiled at all scales

    const int wsl  = (t >= NWT) ? 1 : 0;      // which slice of the pair
    const bool wact = t < 2 * NWT;
    const int wt  = t - NWT * wsl;            // 0..NWT-1
    const int wr  = wt >> 2;
    const int wc4 = wt & 3;
    const size_t rowoff = (size_t)(h0 + wr) * Wp + (w0 + 4 * wc4);

    // Hslide mapping: threads 0..127; hs = slice, hc = col, hg = row group
    const bool hact = t < 128;
    const int hs = t >> 6;
    const int hc = t & 15;
    const int hg = (t >> 4) & 3;

    auto load_slice = [&](int zp, float (&fi)[12], float (&fj)[12]) {
        if (wact) {
            const float* rI = Ib + (size_t)zp * plane + rowoff;
            const float* rJ = Jb + (size_t)zp * plane + rowoff;
            float4 a0 = *reinterpret_cast<const float4*>(rI);
            float4 a1 = *reinterpret_cast<const float4*>(rI + 4);
            float4 a2 = *reinterpret_cast<const float4*>(rI + 8);
            float4 b0 = *reinterpret_cast<const float4*>(rJ);
            float4 b1 = *reinterpret_cast<const float4*>(rJ + 4);
            float4 b2 = *reinterpret_cast<const float4*>(rJ + 8);
            fi[0]=a0.x; fi[1]=a0.y; fi[2]=a0.z; fi[3]=a0.w;
            fi[4]=a1.x; fi[5]=a1.y; fi[6]=a1.z; fi[7]=a1.w;
            fi[8]=a2.x; fi[9]=a2.y; fi[10]=a2.z; fi[11]=a2.w;
            fj[0]=b0.x; fj[1]=b0.y; fj[2]=b0.z; fj[3]=b0.w;
            fj[4]=b1.x; fj[5]=b1.y; fj[6]=b1.z; fj[7]=b1.w;
            fj[8]=b2.x; fj[9]=b2.y; fj[10]=b2.z; fj[11]=b2.w;
        }
    };

    float ring[WIN][5];
    float rs[5];
    #pragma unroll
    for (int s = 0; s < WIN; ++s)
        #pragma unroll
        for (int c = 0; c < 5; ++c) ring[s][c] = 0.f;
    #pragma unroll
    for (int c = 0; c < 5; ++c) rs[c] = 0.f;

    float ccsum = 0.f;

    float fiC[12], fjC[12], fiN[12], fjN[12];
    const int zstart = z0 - RAD;
    const int zend   = z1 + RAD;
    load_slice(zstart + wsl + 4, fiC, fjC);

    for (int zb = zstart; zb < zend; zb += 2 * WIN) {
        #pragma unroll
        for (int i = 0; i < WIN; ++i) {
            const int z = zb + 2 * i;          // slice A (uniform)
            if (z < zend) {
                const bool haveB = (z + 1 < zend);   // uniform
                // ---- 1) prefetch own slice of next pair ----
                const int zpn = min(z + wsl + 2 + 4, Dp - 1);
                load_slice(zpn, fiN, fjN);

                // ---- 2) W phase: both slices concurrently -> wb ----
                if (wact) {
                    float s0 = 0, s1 = 0, s2 = 0, s3 = 0, s4 = 0;
                    #pragma unroll
                    for (int k = 0; k < WIN; ++k) {
                        float a = fiC[OFF + k], bb = fjC[OFF + k];
                        s0 += a; s1 += bb;
                        s2 = fmaf(a, a, s2);
                        s3 = fmaf(bb, bb, s3);
                        s4 = fmaf(bb, a, s4);
                    }
                    float o0[4], o1[4], o2[4], o3[4], o4[4];
                    o0[0]=s0; o1[0]=s1; o2[0]=s2; o3[0]=s3; o4[0]=s4;
                    #pragma unroll
                    for (int m = 1; m < 4; ++m) {
                        float aL = fiC[OFF + m - 1],       bL = fjC[OFF + m - 1];
                        float aR = fiC[OFF + m - 1 + WIN], bR = fjC[OFF + m - 1 + WIN];
                        s0 += aR - aL;
                        s1 += bR - bL;
                        s2 = s2 + aR * aR - aL * aL;
                        s3 = s3 + bR * bR - bL * bL;
                        s4 = s4 + aR * bR - aL * bL;
                        o0[m]=s0; o1[m]=s1; o2[m]=s2; o3[m]=s3; o4[m]=s4;
                    }
                    float* wbW = &wb0123[wsl][0];
                    float* w4W = &wb4[wsl][0];
                    #pragma unroll
                    for (int m = 0; m < 4; ++m) {
                        *reinterpret_cast<float4*>(&wbW[wr * PSTR + 16 * wc4 + 4 * m]) =
                            make_float4(o0[m], o1[m], o2[m], o3[m]);
                    }
                    *reinterpret_cast<float4*>(&w4W[wr * QSTR + 4 * wc4]) =
                        make_float4(o4[0], o4[1], o4[2], o4[3]);
                }
                // ---- 3) bar1 (clobber-free) ----
                __builtin_amdgcn_sched_barrier(0);
                asm volatile("s_waitcnt lgkmcnt(0)");
                __builtin_amdgcn_s_barrier();
                __builtin_amdgcn_sched_barrier(0);
                // ---- 4) Hslide: 4 H-outputs per thread via sliding window ----
                if (hact) {
                    const float* wbS = &wb0123[hs][0];
                    const float* w4S = &wb4[hs][0];
                    float* hwS = &hw0123[hs][0];
                    float* h4S = &hw4[hs][0];
                    const int r0 = 4 * hg;
                    float4 a4 = make_float4(0.f, 0.f, 0.f, 0.f);
                    float a1 = 0.f;
                    float4 st4[3]; float st1[3];
                    #pragma unroll
                    for (int j = 0; j < WIN; ++j) {
                        float4 v = *reinterpret_cast<const float4*>(
                            &wbS[(r0 + j) * PSTR + 4 * hc]);
                        float w = w4S[(r0 + j) * QSTR + hc];
                        a4.x += v.x; a4.y += v.y; a4.z += v.z; a4.w += v.w;
                        a1 += w;
                        if (j < 3) { st4[j] = v; st1[j] = w; }
                    }
                    *reinterpret_cast<float4*>(&hwS[r0 * HSTR + 4 * hc]) = a4;
                    h4S[r0 * H4STR + hc] = a1;
                    #pragma unroll
                    for (int k = 1; k < 4; ++k) {
                        float4 vn = *reinterpret_cast<const float4*>(
                            &wbS[(r0 + WIN - 1 + k) * PSTR + 4 * hc]);
                        float wn = w4S[(r0 + WIN - 1 + k) * QSTR + hc];
                        a4.x += vn.x - st4[k - 1].x;
                        a4.y += vn.y - st4[k - 1].y;
                        a4.z += vn.z - st4[k - 1].z;
                        a4.w += vn.w - st4[k - 1].w;
                        a1 += wn - st1[k - 1];
                        *reinterpret_cast<float4*>(&hwS[(r0 + k) * HSTR + 4 * hc]) = a4;
                        h4S[(r0 + k) * H4STR + hc] = a1;
                    }
                }
                // ---- 5) bar2 (clobber-free) ----
                __builtin_amdgcn_sched_barrier(0);
                asm volatile("s_waitcnt lgkmcnt(0)");
                __builtin_amdgcn_s_barrier();
                __builtin_amdgcn_sched_barrier(0);
                // ---- 6) ring + emit, slice A ----
                {
                    float4 a4 = *reinterpret_cast<const float4*>(
                        &hw0123[0][hh * HSTR + 4 * ww]);
                    float nn4 = hw4[0][hh * H4STR + ww];
                    rs[0] += a4.x - ring[(2 * i) % WIN][0]; ring[(2 * i) % WIN][0] = a4.x;
                    rs[1] += a4.y - ring[(2 * i) % WIN][1]; ring[(2 * i) % WIN][1] = a4.y;
                    rs[2] += a4.z - ring[(2 * i) % WIN][2]; ring[(2 * i) % WIN][2] = a4.z;
                    rs[3] += a4.w - ring[(2 * i) % WIN][3]; ring[(2 * i) % WIN][3] = a4.w;
                    rs[4] += nn4  - ring[(2 * i) % WIN][4]; ring[(2 * i) % WIN][4] = nn4;
                    const int zo = z - RAD;
                    if (valid && zo >= z0) {
                        float muI = rs[0] * invV;
                        float muJ = rs[1] * invV;
                        float sII = rs[2] * invV - muI * muI;
                        float sJJ = rs[3] * invV - muJ * muJ;
                        float s12 = rs[4] * invV - muI * muJ;
                        float cc = (s12 * s12) / fmaxf(sII * sJJ, NCC_EPS);
                        ccsum += cc;
                    }
                }
                // ---- 7) ring + emit, slice B ----
                if (haveB) {
                    float4 a4 = *reinterpret_cast<const float4*>(
                        &hw0123[1][hh * HSTR + 4 * ww]);
                    float nn4 = hw4[1][hh * H4STR + ww];
                    rs[0] += a4.x - ring[(2 * i + 1) % WIN][0]; ring[(2 * i + 1) % WIN][0] = a4.x;
                    rs[1] += a4.y - ring[(2 * i + 1) % WIN][1]; ring[(2 * i + 1) % WIN][1] = a4.y;
                    rs[2] += a4.z - ring[(2 * i + 1) % WIN][2]; ring[(2 * i + 1) % WIN][2] = a4.z;
                    rs[3] += a4.w - ring[(2 * i + 1) % WIN][3]; ring[(2 * i + 1) % WIN][3] = a4.w;
                    rs[4] += nn4  - ring[(2 * i + 1) % WIN][4]; ring[(2 * i + 1) % WIN][4] = nn4;
                    const int zo = z + 1 - RAD;
                    if (valid && zo >= z0) {
                        float muI = rs[0] * invV;
                        float muJ = rs[1] * invV;
                        float sII = rs[2] * invV - muI * muI;
                        float sJJ = rs[3] * invV - muJ * muJ;
                        float s12 = rs[4] * invV - muI * muJ;
                        float cc = (s12 * s12) / fmaxf(sII * sJJ, NCC_EPS);
                        ccsum += cc;
                    }
                }
                // ---- 8) rotate prefetch regs ----
                #pragma unroll
                for (int e = 0; e < 12; ++e) { fiC[e] = fiN[e]; fjC[e] = fjN[e]; }
            }
        }
    }

    for (int off = 32; off > 0; off >>= 1)
        ccsum += __shfl_down(ccsum, off);
    const int wid = t >> 6, lane = t & 63;
    if (lane == 0) red[wid] = ccsum;
    __syncthreads();
    if (t == 0) {
        float s = red[0] + red[1] + red[2] + red[3];
        atomicAdd(acc, (double)s);
    }
}

// ===========================================================================
// Padded-pyramid NCC (1 slice/barrier) for scales 1/2.
// ===========================================================================
template<int WIN>
__global__ __launch_bounds__(256)
void ncc_pad_kernel(const float* __restrict__ Pi, const float* __restrict__ Pj,
                    int Dp, int Hp, int Wp, int Dreal, int Wreal,
                    int tilesH, int tilesW, int chunksD, int chunkLen,
                    double* __restrict__ acc)
{
    constexpr int RAD  = WIN / 2;
    constexpr int TH = 16, TW = 16;
    constexpr int WROWS = TH + 2 * RAD;
    constexpr int PSTR = 68;
    constexpr int QSTR = 16;
    constexpr int OFF  = 4 - RAD;
    constexpr int NWT  = WROWS * 4;
    constexpr float invV = 1.0f / (float)(WIN * WIN * WIN);

    __shared__ __align__(16) float wb0123[2][WROWS * PSTR];
    __shared__ __align__(16) float wb4[2][WROWS * QSTR];
    __shared__ float red[4];

    int bid = blockIdx.x;
    int tw = bid % tilesW; bid /= tilesW;
    int th = bid % tilesH; bid /= tilesH;
    int cd = bid % chunksD; bid /= chunksD;
    int b  = bid;

    const int h0 = th * TH, w0 = tw * TW;
    const int z0 = cd * chunkLen;
    const int z1 = min(z0 + chunkLen, Dreal);

    const size_t plane = (size_t)Hp * Wp;
    const float* Ib = Pi + (size_t)b * Dp * plane;
    const float* Jb = Pj + (size_t)b * Dp * plane;

    const int t  = threadIdx.x;
    const int hh = t >> 4, ww = t & 15;
    const bool valid = (w0 + ww) < Wreal;

    const int wr  = t >> 2;
    const int wc4 = t & 3;
    const bool wact = t < NWT;
    const size_t rowoff = (size_t)(h0 + wr) * Wp + (w0 + 4 * wc4);

    auto load_slice = [&](int zp, float (&fi)[12], float (&fj)[12]) {
        if (wact) {
            const float* rI = Ib + (size_t)zp * plane + rowoff;
            const float* rJ = Jb + (size_t)zp * plane + rowoff;
            float4 a0 = *reinterpret_cast<const float4*>(rI);
            float4 a1 = *reinterpret_cast<const float4*>(rI + 4);
            float4 a2 = *reinterpret_cast<const float4*>(rI + 8);
            float4 b0 = *reinterpret_cast<const float4*>(rJ);
            float4 b1 = *reinterpret_cast<const float4*>(rJ + 4);
            float4 b2 = *reinterpret_cast<const float4*>(rJ + 8);
            fi[0]=a0.x; fi[1]=a0.y; fi[2]=a0.z; fi[3]=a0.w;
            fi[4]=a1.x; fi[5]=a1.y; fi[6]=a1.z; fi[7]=a1.w;
            fi[8]=a2.x; fi[9]=a2.y; fi[10]=a2.z; fi[11]=a2.w;
            fj[0]=b0.x; fj[1]=b0.y; fj[2]=b0.z; fj[3]=b0.w;
            fj[4]=b1.x; fj[5]=b1.y; fj[6]=b1.z; fj[7]=b1.w;
            fj[8]=b2.x; fj[9]=b2.y; fj[10]=b2.z; fj[11]=b2.w;
        }
    };

    float ring[WIN][5];
    float rs[5];
    #pragma unroll
    for (int s = 0; s < WIN; ++s)
        #pragma unroll
        for (int c = 0; c < 5; ++c) ring[s][c] = 0.f;
    #pragma unroll
    for (int c = 0; c < 5; ++c) rs[c] = 0.f;

    float ccsum = 0.f;

    float fiC[12], fjC[12], fiN[12], fjN[12];
    const int zend = z1 + RAD;
    load_slice(z0 - RAD + 4, fiC, fjC);

    for (int zb = z0 - RAD; zb < zend; zb += WIN) {
        #pragma unroll
        for (int ph = 0; ph < WIN; ++ph) {
            const int z = zb + ph;
            if (z < zend) {
                const int zpn = min(z + 5, Dp - 1);
                load_slice(zpn, fiN, fjN);

                const int par = (z + 4) & 1;
                float n0, n1, n2, n3, n4;
                if (wact) {
                    float s0 = 0, s1 = 0, s2 = 0, s3 = 0, s4 = 0;
                    #pragma unroll
                    for (int k = 0; k < WIN; ++k) {
                        float a = fiC[OFF + k], bb = fjC[OFF + k];
                        s0 += a; s1 += bb;
                        s2 = fmaf(a, a, s2);
                        s3 = fmaf(bb, bb, s3);
                        s4 = fmaf(a, bb, s4);
                    }
                    float o0[4], o1[4], o2[4], o3[4], o4[4];
                    o0[0]=s0; o1[0]=s1; o2[0]=s2; o3[0]=s3; o4[0]=s4;
                    #pragma unroll
                    for (int m = 1; m < 4; ++m) {
                        float aL = fiC[OFF + m - 1],       bL = fjC[OFF + m - 1];
                        float aR = fiC[OFF + m - 1 + WIN], bR = fjC[OFF + m - 1 + WIN];
                        s0 += aR - aL;
                        s1 += bR - bL;
                        s2 = s2 + aR * aR - aL * aL;
                        s3 = s3 + bR * bR - bL * bL;
                        s4 = s4 + aR * bR - aL * bL;
                        o0[m]=s0; o1[m]=s1; o2[m]=s2; o3[m]=s3; o4[m]=s4;
                    }
                    #pragma unroll
                    for (int m = 0; m < 4; ++m) {
                        *reinterpret_cast<float4*>(&wb0123[par][wr * PSTR + 16 * wc4 + 4 * m]) =
                            make_float4(o0[m], o1[m], o2[m], o3[m]);
                    }
                    *reinterpret_cast<float4*>(&wb4[par][wr * QSTR + 4 * wc4]) =
                        make_float4(o4[0], o4[1], o4[2], o4[3]);
                }
                __builtin_amdgcn_sched_barrier(0);
                asm volatile("s_waitcnt lgkmcnt(0)");
                __builtin_amdgcn_s_barrier();
                __builtin_amdgcn_sched_barrier(0);
                {
                    float4 a4 = make_float4(0.f, 0.f, 0.f, 0.f);
                    float nn4 = 0.f;
                    #pragma unroll
                    for (int dh = 0; dh < WIN; ++dh) {
                        float4 v = *reinterpret_cast<const float4*>(
                            &wb0123[par][(hh + dh) * PSTR + 4 * ww]);
                        a4.x += v.x; a4.y += v.y; a4.z += v.z; a4.w += v.w;
                        nn4 += wb4[par][(hh + dh) * QSTR + ww];
                    }
                    n0 = a4.x; n1 = a4.y; n2 = a4.z; n3 = a4.w; n4 = nn4;
                }
                rs[0] += n0 - ring[ph][0]; ring[ph][0] = n0;
                rs[1] += n1 - ring[ph][1]; ring[ph][1] = n1;
                rs[2] += n2 - ring[ph][2]; ring[ph][2] = n2;
                rs[3] += n3 - ring[ph][3]; ring[ph][3] = n3;
                rs[4] += n4 - ring[ph][4]; ring[ph][4] = n4;

                const int zo = z - RAD;
                if (valid && zo >= z0) {
                    float muI = rs[0] * invV;
                    float muJ = rs[1] * invV;
                    float sII = rs[2] * invV - muI * muI;
                    float sJJ = rs[3] * invV - muJ * muJ;
                    float s12 = rs[4] * invV - muI * muJ;
                    float cc = (s12 * s12) / fmaxf(sII * sJJ, NCC_EPS);
                    ccsum += cc;
                }
                #pragma unroll
                for (int e = 0; e < 12; ++e) { fiC[e] = fiN[e]; fjC[e] = fjN[e]; }
            }
        }
    }

    for (int off = 32; off > 0; off >>= 1)
        ccsum += __shfl_down(ccsum, off);
    const int wid = t >> 6, lane = t & 63;
    if (lane == 0) red[wid] = ccsum;
    __syncthreads();
    if (t == 0) {
        float s = red[0] + red[1] + red[2] + red[3];
        atomicAdd(acc, (double)s);
    }
}

// Pad-copy scale-0 inputs into [Dp][Hp][Wp] with zero borders (both arrays).
__global__ void pad_kernel(const float* __restrict__ inA, const float* __restrict__ inB,
                           float* __restrict__ outA, float* __restrict__ outB,
                           int D, int H, int W, int Dp, int Hp, int Wp, int nchunks)
{
    int idx = blockIdx.x * 256 + threadIdx.x;
    if (idx >= 2 * nchunks) return;
    const bool isB = idx >= nchunks;
    int k = isB ? idx - nchunks : idx;
    const float* in = isB ? inB : inA;
    float* out = isB ? outB : outA;
    const int WC = Wp / 4;
    int wc = k % WC; int tmp = k / WC;
    int hp = tmp % Hp; tmp /= Hp;
    int zp = tmp % Dp; int b = tmp / Dp;
    int z = zp - 4, h = hp - 4, w0 = 4 * wc - 4;
    float4 v = make_float4(0.f, 0.f, 0.f, 0.f);
    if (z >= 0 && z < D && h >= 0 && h < H && w0 >= 0 && w0 + 4 <= W)
        v = *reinterpret_cast<const float4*>(in + ((size_t)(b * D + z) * H + h) * W + w0);
    *reinterpret_cast<float4*>(out + ((size_t)(b * Dp + zp) * Hp + hp) * Wp + 4 * wc) = v;
}

// avg_pool3d k=3 s=2 pad=1 count_include_pad=False; padded in -> padded out.
__global__ void pool_pad_kernel(const float* __restrict__ inA, const float* __restrict__ inB,
                                float* __restrict__ outA, float* __restrict__ outB,
                                int D, int H, int W, int iDp, int iHp, int iWp,
                                int oD, int oH, int oW, int oDp, int oHp, int oWp,
                                int total)
{
    int idx0 = blockIdx.x * 256 + threadIdx.x;
    if (idx0 >= 2 * total) return;
    const bool isB = idx0 >= total;
    int idx = isB ? idx0 - total : idx0;
    const float* in = isB ? inB : inA;
    float* out = isB ? outB : outA;

    int ow = idx % oW; int tmp = idx / oW;
    int oh = tmp % oH; tmp /= oH;
    int od = tmp % oD; int b = tmp / oD;

    const size_t ip = (size_t)iHp * iWp;
    const float* ib = in + (size_t)b * iDp * ip;
    float s = 0.f;
    #pragma unroll
    for (int dd = 0; dd < 3; ++dd)
        #pragma unroll
        for (int dh = 0; dh < 3; ++dh) {
            const float* r = ib + (size_t)(2 * od + 3 + dd) * ip
                                + (size_t)(2 * oh + 3 + dh) * iWp + (2 * ow + 3);
            s += r[0] + r[1] + r[2];
        }
    int dlo = max(2 * od - 1, 0), dhi = min(2 * od + 2, D);
    int hlo = max(2 * oh - 1, 0), hhi = min(2 * oh + 2, H);
    int wlo = max(2 * ow - 1, 0), whi = min(2 * ow + 2, W);
    int cnt = (dhi - dlo) * (hhi - hlo) * (whi - wlo);
    out[((size_t)(b * oDp + od + 4) * oHp + (oh + 4)) * oWp + (ow + 4)] = s / (float)cnt;
}

// ===========================================================================
// FALLBACK PATH (small workspace): bounded kernel, verified passing.
// ===========================================================================
template<int WIN>
__global__ __launch_bounds__(256)
void ncc_scale_kernel(const float* __restrict__ I, const float* __restrict__ J,
                      int D, int H, int W,
                      int tilesH, int tilesW, int chunksD, int chunkLen,
                      double* __restrict__ acc)
{
    constexpr int RAD  = WIN / 2;
    constexpr int TH = 16, TW = 16;
    constexpr int WROWS = TH + 2 * RAD;
    constexpr int PSTR = 68;
    constexpr int QSTR = 16;
    constexpr int OFF  = 4 - RAD;
    constexpr int NWT  = WROWS * 4;
    constexpr float invV = 1.0f / (float)(WIN * WIN * WIN);

    __shared__ __align__(16) float wb0123[2][WROWS * PSTR];
    __shared__ __align__(16) float wb4[2][WROWS * QSTR];
    __shared__ float red[4];

    int bid = blockIdx.x;
    int tw = bid % tilesW; bid /= tilesW;
    int th = bid % tilesH; bid /= tilesH;
    int cd = bid % chunksD; bid /= chunksD;
    int b  = bid;

    const int h0 = th * TH, w0 = tw * TW;
    const int z0 = cd * chunkLen;
    const int z1 = min(z0 + chunkLen, D);

    const size_t plane = (size_t)H * W;
    const float* Ib = I + (size_t)b * D * plane;
    const float* Jb = J + (size_t)b * D * plane;

    const int t  = threadIdx.x;
    const int hh = t >> 4, ww = t & 15;
    const bool valid = (h0 + hh) < H && (w0 + ww) < W;

    const int wr  = t >> 2;
    const int wc4 = t & 3;
    const bool wact = t < NWT;
    const int wbase = w0 + 4 * wc4 - 4;
    const int wghr  = h0 + wr - RAD;

    auto load_slice = [&](int z, float (&fi)[12], float (&fj)[12]) {
        const bool zok = (z >= 0) && (z < D);
        if (zok && wact && wghr >= 0 && wghr < H) {
            const float* rowI = Ib + (size_t)z * plane + (size_t)wghr * W;
            const float* rowJ = Jb + (size_t)z * plane + (size_t)wghr * W;
            if (wbase >= 0 && wbase + 12 <= W) {
                float4 a0 = *reinterpret_cast<const float4*>(rowI + wbase);
                float4 a1 = *reinterpret_cast<const float4*>(rowI + wbase + 4);
                float4 a2 = *reinterpret_cast<const float4*>(rowI + wbase + 8);
                float4 b0 = *reinterpret_cast<const float4*>(rowJ + wbase);
                float4 b1 = *reinterpret_cast<const float4*>(rowJ + wbase + 4);
                float4 b2 = *reinterpret_cast<const float4*>(rowJ + wbase + 8);
                fi[0]=a0.x; fi[1]=a0.y; fi[2]=a0.z; fi[3]=a0.w;
                fi[4]=a1.x; fi[5]=a1.y; fi[6]=a1.z; fi[7]=a1.w;
                fi[8]=a2.x; fi[9]=a2.y; fi[10]=a2.z; fi[11]=a2.w;
                fj[0]=b0.x; fj[1]=b0.y; fj[2]=b0.z; fj[3]=b0.w;
                fj[4]=b1.x; fj[5]=b1.y; fj[6]=b1.z; fj[7]=b1.w;
                fj[8]=b2.x; fj[9]=b2.y; fj[10]=b2.z; fj[11]=b2.w;
            } else {
                #pragma unroll
                for (int e = 0; e < 12; ++e) {
                    int cg = wbase + e;
                    bool ok = (cg >= 0) && (cg < W);
                    fi[e] = ok ? rowI[cg] : 0.f;
                    fj[e] = ok ? rowJ[cg] : 0.f;
                }
            }
        } else {
            #pragma unroll
            for (int e = 0; e < 12; ++e) { fi[e] = 0.f; fj[e] = 0.f; }
        }
    };

    float ring[WIN][5];
    float rs[5];
    #pragma unroll
    for (int s = 0; s < WIN; ++s)
        #pragma unroll
        for (int c = 0; c < 5; ++c) ring[s][c] = 0.f;
    #pragma unroll
    for (int c = 0; c < 5; ++c) rs[c] = 0.f;

    float ccsum = 0.f;

    float fiC[12], fjC[12], fiN[12], fjN[12];
    const int zend = z1 + RAD;
    load_slice(z0 - RAD, fiC, fjC);

    for (int zb = z0 - RAD; zb < zend; zb += WIN) {
        #pragma unroll
        for (int ph = 0; ph < WIN; ++ph) {
            const int z = zb + ph;
            if (z < zend) {
                const bool zin = (z >= 0) && (z < D);
                load_slice((z + 1 < zend) ? z + 1 : -1, fiN, fjN);
                float n0 = 0, n1 = 0, n2 = 0, n3 = 0, n4 = 0;
                if (zin) {
                    const int par = (z + 64) & 1;
                    if (wact) {
                        float s0 = 0, s1 = 0, s2 = 0, s3 = 0, s4 = 0;
                        #pragma unroll
                        for (int k = 0; k < WIN; ++k) {
                            float a = fiC[OFF + k], bb = fjC[OFF + k];
                            s0 += a; s1 += bb;
                            s2 = fmaf(a, a, s2);
                            s3 = fmaf(bb, bb, s3);
                            s4 = fmaf(a, bb, s4);
                        }
                        float o0[4], o1[4], o2[4], o3[4], o4[4];
                        o0[0]=s0; o1[0]=s1; o2[0]=s2; o3[0]=s3; o4[0]=s4;
                        #pragma unroll
                        for (int m = 1; m < 4; ++m) {
                            float aL = fiC[OFF + m - 1],       bL = fjC[OFF + m - 1];
                            float aR = fiC[OFF + m - 1 + WIN], bR = fjC[OFF + m - 1 + WIN];
                            s0 += aR - aL;
                            s1 += bR - bL;
                            s2 = s2 + aR * aR - aL * aL;
                            s3 = s3 + bR * bR - bL * bL;
                            s4 = s4 + aR * bR - aL * bL;
                            o0[m]=s0; o1[m]=s1; o2[m]=s2; o3[m]=s3; o4[m]=s4;
                        }
                        #pragma unroll
                        for (int m = 0; m < 4; ++m) {
                            *reinterpret_cast<float4*>(&wb0123[par][wr * PSTR + 16 * wc4 + 4 * m]) =
                                make_float4(o0[m], o1[m], o2[m], o3[m]);
                        }
                        *reinterpret_cast<float4*>(&wb4[par][wr * QSTR + 4 * wc4]) =
                            make_float4(o4[0], o4[1], o4[2], o4[3]);
                    }
                    __syncthreads();
                    float4 a4 = make_float4(0.f, 0.f, 0.f, 0.f);
                    #pragma unroll
                    for (int dh = 0; dh < WIN; ++dh) {
                        float4 v = *reinterpret_cast<const float4*>(
                            &wb0123[par][(hh + dh) * PSTR + 4 * ww]);
                        a4.x += v.x; a4.y += v.y; a4.z += v.z; a4.w += v.w;
                        n4 += wb4[par][(hh + dh) * QSTR + ww];
                    }
                    n0 = a4.x; n1 = a4.y; n2 = a4.z; n3 = a4.w;
                }
                rs[0] += n0 - ring[ph][0]; ring[ph][0] = n0;
                rs[1] += n1 - ring[ph][1]; ring[ph][1] = n1;
                rs[2] += n2 - ring[ph][2]; ring[ph][2] = n2;
                rs[3] += n3 - ring[ph][3]; ring[ph][3] = n3;
                rs[4] += n4 - ring[ph][4]; ring[ph][4] = n4;

                const int zo = z - RAD;
                if (valid && zo >= z0) {
                    float muI = rs[0] * invV;
                    float muJ = rs[1] * invV;
                    float sII = rs[2] * invV - muI * muI;
                    float sJJ = rs[3] * invV - muJ * muJ;
                    float s12 = rs[4] * invV - muI * muJ;
                    float cc = (s12 * s12) / fmaxf(sII * sJJ, NCC_EPS);
                    ccsum += cc;
                }
                #pragma unroll
                for (int e = 0; e < 12; ++e) { fiC[e] = fiN[e]; fjC[e] = fjN[e]; }
            }
        }
    }

    for (int off = 32; off > 0; off >>= 1)
        ccsum += __shfl_down(ccsum, off);
    const int wid = t >> 6, lane = t & 63;
    if (lane == 0) red[wid] = ccsum;
    __syncthreads();
    if (t == 0) {
        float s = red[0] + red[1] + red[2] + red[3];
        atomicAdd(acc, (double)s);
    }
}

__global__ void pool_kernel2(const float* __restrict__ inA, const float* __restrict__ inB,
                             float* __restrict__ outA, float* __restrict__ outB,
                             int D, int H, int W, int oD, int oH, int oW, int total)
{
    int idx0 = blockIdx.x * 256 + threadIdx.x;
    if (idx0 >= 2 * total) return;
    const bool isB = idx0 >= total;
    int idx = isB ? idx0 - total : idx0;
    const float* in = isB ? inB : inA;
    float* out = isB ? outB : outA;

    int ow = idx % oW; int tmp = idx / oW;
    int oh = tmp % oH; tmp /= oH;
    int od = tmp % oD; int b = tmp / oD;

    int dlo = max(2 * od - 1, 0), dhi = min(2 * od + 2, D);
    int hlo = max(2 * oh - 1, 0), hhi = min(2 * oh + 2, H);
    int wlo = max(2 * ow - 1, 0), whi = min(2 * ow + 2, W);

    const float* ib = in + (size_t)b * D * H * W;
    float s = 0.f;
    for (int d = dlo; d < dhi; ++d)
        for (int h = hlo; h < hhi; ++h)
            for (int w = wlo; w < whi; ++w)
                s += ib[((size_t)d * H + h) * W + w];
    int cnt = (dhi - dlo) * (hhi - hlo) * (whi - wlo);
    out[idx] = s / (float)cnt;
}

__global__ void finalize_kernel(const double* __restrict__ acc, float* __restrict__ out)
{
    double m = acc[0] / 9830400.0 + acc[1] / 1228800.0 + acc[2] / 153600.0;
    out[0] = (float)(-m / 3.0);
}

extern "C" void kernel_launch(void* const* d_in, const int* in_sizes, int n_in,
                              void* d_out, int out_size, void* d_ws, size_t ws_size,
                              hipStream_t stream)
{
    const float* I0 = (const float*)d_in[0];
    const float* J0 = (const float*)d_in[1];
    float* out = (float*)d_out;

    char* ws = (char*)d_ws;
    double* acc = (double*)ws;
    hipMemsetAsync(acc, 0, 3 * sizeof(double), stream);

    const size_t P0SZ = (size_t)2 * 168 * 200 * 168;
    const size_t P1SZ = (size_t)2 * 88 * 104 * 88;
    const size_t P2SZ = (size_t)2 * 48 * 56 * 56;
    const size_t need_pad = 256 + (2 * P0SZ + 2 * P1SZ + 2 * P2SZ) * sizeof(float);

    if (ws_size >= need_pad) {
        // ---------------- PADDED PATH ----------------
        float* P0I = (float*)(ws + 256);
        float* P0J = P0I + P0SZ;
        float* P1I = P0J + P0SZ;
        float* P1J = P1I + P1SZ;
        float* P2I = P1J + P1SZ;
        float* P2J = P2I + P2SZ;

        hipMemsetAsync(P1I, 0, (2 * P1SZ + 2 * P2SZ) * sizeof(float), stream);

        {
            int nchunks = (int)(P0SZ / 4);
            int blocks = (2 * nchunks + 255) / 256;
            pad_kernel<<<blocks, 256, 0, stream>>>(I0, J0, P0I, P0J,
                                                   160, 192, 160, 168, 200, 168, nchunks);
        }
        // scale 0: 2-slice + hierarchical-H, 960 blocks
        ncc_pad3_kernel<9><<<2 * 12 * 10 * 4, 256, 0, stream>>>(
            P0I, P0J, 168, 200, 168, 160, 160, 12, 10, 4, 40, acc + 0);
        {
            int total = 2 * 80 * 96 * 80;
            int blocks = (2 * total + 255) / 256;
            pool_pad_kernel<<<blocks, 256, 0, stream>>>(P0I, P0J, P1I, P1J,
                                                        160, 192, 160, 168, 200, 168,
                                                        80, 96, 80, 88, 104, 88, total);
        }
        ncc_pad_kernel<7><<<2 * 6 * 5 * 10, 256, 0, stream>>>(
            P1I, P1J, 88, 104, 88, 80, 80, 6, 5, 10, 8, acc + 1);
        {
            int total = 2 * 40 * 48 * 40;
            int blocks = (2 * total + 255) / 256;
            pool_pad_kernel<<<blocks, 256, 0, stream>>>(P1I, P1J, P2I, P2J,
                                                        80, 96, 80, 88, 104, 88,
                                                        40, 48, 40, 48, 56, 56, total);
        }
        ncc_pad_kernel<5><<<2 * 3 * 3 * 10, 256, 0, stream>>>(
            P2I, P2J, 48, 56, 56, 40, 40, 3, 3, 10, 4, acc + 2);
    } else {
        // ---------------- FALLBACK (bounded path) ----------------
        float* I1 = (float*)(ws + 256);
        float* J1 = I1 + (size_t)2 * 80 * 96 * 80;
        float* I2 = J1 + (size_t)2 * 80 * 96 * 80;
        float* J2 = I2 + (size_t)2 * 40 * 48 * 40;

        ncc_scale_kernel<9><<<2 * 12 * 10 * 6, 256, 0, stream>>>(
            I0, J0, 160, 192, 160, 12, 10, 6, 27, acc + 0);
        {
            int total = 2 * 80 * 96 * 80;
            int blocks = (2 * total + 255) / 256;
            pool_kernel2<<<blocks, 256, 0, stream>>>(I0, J0, I1, J1,
                                                     160, 192, 160, 80, 96, 80, total);
        }
        ncc_scale_kernel<7><<<2 * 6 * 5 * 10, 256, 0, stream>>>(
            I1, J1, 80, 96, 80, 6, 5, 10, 8, acc + 1);
        {
            int total = 2 * 40 * 48 * 40;
            int blocks = (2 * total + 255) / 256;
            pool_kernel2<<<blocks, 256, 0, stream>>>(I1, J1, I2, J2,
                                                     80, 96, 80, 40, 48, 40, total);
        }
        ncc_scale_kernel<5><<<2 * 3 * 3 * 10, 256, 0, stream>>>(
            I2, J2, 40, 48, 40, 3, 3, 10, 4, acc + 2);
    }

    finalize_kernel<<<1, 1, 0, stream>>>(acc, out);
}